// Round 1
// baseline (166.953 us; speedup 1.0000x reference)
//
#include <hip/hip_runtime.h>
#include <hip/hip_bf16.h>
#include <math.h>

// B=2, T=2048, C=1024, H=16, D=64
typedef __attribute__((ext_vector_type(8))) short s8v;    // 8 bf16
typedef __attribute__((ext_vector_type(4))) float f4v;    // 4 fp32
typedef __attribute__((ext_vector_type(16))) float f16v;  // 16 fp32 (32x32 C/D)
typedef unsigned short ush;
typedef unsigned int u32;

#define QSCALE 0.180336880f   /* 0.125 * log2(e): S emerges in log2 domain */

static __device__ __forceinline__ ush f2bf(float f) {
    u32 x = __builtin_bit_cast(u32, f);
    return (ush)((x + 0x7fffu + ((x >> 16) & 1u)) >> 16);
}
static __device__ __forceinline__ u32 bfpack(float lo, float hi) {
    u32 a = __builtin_bit_cast(u32, lo) + 0x8000u;
    u32 b = __builtin_bit_cast(u32, hi) + 0x8000u;
    return __builtin_amdgcn_perm(b, a, 0x07060302);
}
static __device__ __forceinline__ void gl_lds16(const void* g, void* l) {
    __builtin_amdgcn_global_load_lds(
        (const __attribute__((address_space(1))) u32*)g,
        (__attribute__((address_space(3))) u32*)l, 16, 0, 0);
}
#if __has_builtin(__builtin_amdgcn_exp2f)
#define EXP2F(x) __builtin_amdgcn_exp2f(x)
#else
#define EXP2F(x) exp2f(x)
#endif

// ---------------------------------------------------------------------------
// Prep A (fused): blocks [0,2048): Xb = bf16(X); [2048,2560): Wt[n][k]=W[k][n]
// ---------------------------------------------------------------------------
__global__ __launch_bounds__(256) void prepA_kernel(
    const float* __restrict__ X, const float* __restrict__ W,
    ush* __restrict__ Xb, ush* __restrict__ Wt)
{
    __shared__ float Ts[64][68];
    const int tid = threadIdx.x;
    const int bid = blockIdx.x;
    if (bid < 2048) {
        const size_t i = ((size_t)bid * 256 + tid) * 8;
        float4 v0 = *(const float4*)(X + i);
        float4 v1 = *(const float4*)(X + i + 4);
        uint4 o;
        o.x = bfpack(v0.x, v0.y); o.y = bfpack(v0.z, v0.w);
        o.z = bfpack(v1.x, v1.y); o.w = bfpack(v1.z, v1.w);
        *(uint4*)(Xb + i) = o;
    } else {
        const int id = bid - 2048;           // 512 blocks: 32 x 16
        const int n0 = (id & 31) * 64, k0 = (id >> 5) * 64;
        #pragma unroll
        for (int p = 0; p < 4; ++p) {
            const int idx = p * 256 + tid;
            const int kr = idx >> 4, nc4 = idx & 15;
            float4 v = *(const float4*)(W + (size_t)(k0 + kr) * 2048 + n0 + nc4 * 4);
            Ts[kr][nc4 * 4 + 0] = v.x; Ts[kr][nc4 * 4 + 1] = v.y;
            Ts[kr][nc4 * 4 + 2] = v.z; Ts[kr][nc4 * 4 + 3] = v.w;
        }
        __syncthreads();
        const int n = tid >> 2, kb = (tid & 3) * 16;
        #pragma unroll
        for (int p = 0; p < 4; ++p) {
            const int k = kb + p * 4;
            ushort4 o;
            o.x = f2bf(Ts[k + 0][n]); o.y = f2bf(Ts[k + 1][n]);
            o.z = f2bf(Ts[k + 2][n]); o.w = f2bf(Ts[k + 3][n]);
            *(ushort4*)(Wt + (size_t)(n0 + n) * 1024 + k0 + k) = o;
        }
    }
}

// ---------------------------------------------------------------------------
// Prep B: Vt[b][h][d][t] = bf16(x_v[b][t][h*64+d]).  grid (32, 32).
// (runs after gemm so Vt may overlay Xb in the workspace)
// ---------------------------------------------------------------------------
__global__ __launch_bounds__(256) void vt_kernel(
    const float* __restrict__ XV, ush* __restrict__ Vt)
{
    __shared__ float Ts[64][68];
    const int tid = threadIdx.x;
    const int t0 = blockIdx.x * 64;
    const int bh = blockIdx.y;
    const int b = bh >> 4, h = bh & 15;
    #pragma unroll
    for (int p = 0; p < 4; ++p) {
        const int idx = p * 256 + tid;
        const int tr = idx >> 4, dc4 = idx & 15;
        float4 v = *(const float4*)(XV + (size_t)(b * 2048 + t0 + tr) * 1024
                                    + h * 64 + dc4 * 4);
        Ts[tr][dc4 * 4 + 0] = v.x; Ts[tr][dc4 * 4 + 1] = v.y;
        Ts[tr][dc4 * 4 + 2] = v.z; Ts[tr][dc4 * 4 + 3] = v.w;
    }
    __syncthreads();
    const int d = tid >> 2, tb = (tid & 3) * 16;
    #pragma unroll
    for (int p = 0; p < 4; ++p) {
        const int tq = tb + p * 4;
        ushort4 o;
        o.x = f2bf(Ts[tq + 0][d]); o.y = f2bf(Ts[tq + 1][d]);
        o.z = f2bf(Ts[tq + 2][d]); o.w = f2bf(Ts[tq + 3][d]);
        *(ushort4*)(Vt + (size_t)((b * 16 + h) * 64 + d) * 2048 + t0 + tq) = o;
    }
}

// ---------------------------------------------------------------------------
// MFMA GEMM (m97 structure): C = Xb @ Wt^T + bias; Q scaled by 0.125*log2e.
// ---------------------------------------------------------------------------
__global__ __launch_bounds__(256) void gemm_kernel(
    const ush* __restrict__ Xb, const ush* __restrict__ Wt,
    const float* __restrict__ bias,
    ush* __restrict__ Qb, ush* __restrict__ Kb)
{
    __shared__ ush As[128 * 32];
    __shared__ ush Bs[128 * 32];

    const int tid = threadIdx.x;
    const int wid = tid >> 6, lane = tid & 63;
    const int quad = lane >> 4, l15 = lane & 15;
    const int wm = wid >> 1, wn = wid & 1;
    const int m0 = blockIdx.y * 128, n0 = blockIdx.x * 128;

    const int lrow = lane >> 2;
    const int lkk = (lane & 3) * 8;
    const size_t arow = (size_t)(m0 + wid * 32 + lrow);
    const size_t brow = (size_t)(n0 + wid * 32 + lrow);
    ush* AsW = &As[wid * 1024];
    ush* BsW = &Bs[wid * 1024];

    f4v acc[4][4];
    #pragma unroll
    for (int i = 0; i < 4; ++i)
        #pragma unroll
        for (int j = 0; j < 4; ++j) acc[i][j] = (f4v){0.f, 0.f, 0.f, 0.f};

    for (int k0 = 0; k0 < 1024; k0 += 32) {
        gl_lds16(Xb + arow * 1024 + k0 + lkk, AsW);
        gl_lds16(Xb + (arow + 16) * 1024 + k0 + lkk, AsW + 512);
        gl_lds16(Wt + brow * 1024 + k0 + lkk, BsW);
        gl_lds16(Wt + (brow + 16) * 1024 + k0 + lkk, BsW + 512);
        __syncthreads();

        s8v a[4], bf[4];
        #pragma unroll
        for (int i = 0; i < 4; ++i)
            a[i] = *(const s8v*)&As[(wm * 64 + i * 16 + l15) * 32 + quad * 8];
        #pragma unroll
        for (int j = 0; j < 4; ++j)
            bf[j] = *(const s8v*)&Bs[(wn * 64 + j * 16 + l15) * 32 + quad * 8];
        #pragma unroll
        for (int i = 0; i < 4; ++i)
            #pragma unroll
            for (int j = 0; j < 4; ++j)
                acc[i][j] = __builtin_amdgcn_mfma_f32_16x16x32_bf16(
                    a[i], bf[j], acc[i][j], 0, 0, 0);
        __syncthreads();
    }

    #pragma unroll
    for (int j = 0; j < 4; ++j) {
        const int n = n0 + wn * 64 + j * 16 + l15;
        const float bv = bias[n];
        const bool is_k = n >= 1024;
        const int nn = n & 1023;
        const int h = nn >> 6, d = nn & 63;
        ush* dst = is_k ? Kb : Qb;
        #pragma unroll
        for (int i = 0; i < 4; ++i) {
            const int mrow = m0 + wm * 64 + i * 16 + quad * 4;
            #pragma unroll
            for (int r = 0; r < 4; ++r) {
                const int m = mrow + r;
                const int b = m >> 11, t = m & 2047;
                float val = acc[i][j][r] + bv;
                if (!is_k) val *= QSCALE;
                dst[(size_t)((b * 16 + h) * 2048 + t) * 64 + d] = f2bf(val);
            }
        }
    }
}

// ---------------------------------------------------------------------------
// MFMA causal flash attention, 32x32x16, S^T form, 128 q-rows per block.
//   v2: 2-stage software pipeline — S(kt+1) MFMA issued BEFORE softmax(kt),
//   so the QK^T MFMA executes under the softmax VALU (exp2-heavy) of the
//   previous tile. K staged 2 tiles ahead, V 1 ahead; still 2 LDS buffers
//   each (K(kt+2) reuses the dead K(kt) slot; barrier per tile separates all
//   cross-wave reuse). Defer-max (THR=8 in log2 domain) skips the O/l
//   rescale when the wave-wide max growth is <= 2^8. setprio(1) wraps the
//   MFMA clusters.
// ---------------------------------------------------------------------------
__global__ __launch_bounds__(256, 2) void attn_kernel(
    const ush* __restrict__ Qb, const ush* __restrict__ Kb,
    const ush* __restrict__ Vt, float* __restrict__ Y)
{
    // SMEM carve: Kbuf 2x4096, Vbuf 2x4096, Pq 4x(32*72)  (51200 B total)
    __shared__ ush SMEM[25600];
    ush* Kbuf = SMEM;                 // [buf*4096 + row*64 + elem]
    ush* Vbuf = SMEM + 8192;
    ush* Pq   = SMEM + 16384;        // + w*2304

    const int tid = threadIdx.x;
    const int w = tid >> 6, lane = tid & 63;
    const int l31 = lane & 31, hi = lane >> 5;     // hi in {0,1}

    // block mapping: CU gets blocks i and i+256 with qt summing to 15
    const int idx = blockIdx.x;
    const int half = idx >> 8, pair = idx & 255;
    const int qt = half ? (pair & 15) : 15 - (pair & 15);
    const int bh = (pair >> 4) + half * 16;
    const int b = bh >> 4, h = bh & 15;
    const int q0 = qt * 128;
    const int ktmax = 2 * qt + 1;

    const ush* Qg = Qb + (size_t)bh * 2048 * 64;
    const ush* Kg = Kb + (size_t)bh * 2048 * 64;
    const ush* Vg = Vt + (size_t)bh * 64 * 2048;

    ush* Pw = Pq + w * 2304;

    // ---- stage Q rows (wave-private) and pull B-frags into regs
    {
        const int r8q = lane >> 3, c8 = lane & 7;
        #pragma unroll
        for (int p = 0; p < 4; ++p) {
            const int row = p * 8 + r8q;
            uint4 v = *(const uint4*)(Qg + (size_t)(q0 + w * 32 + row) * 64 + c8 * 8);
            *(uint4*)&Pw[row * 72 + c8 * 8] = v;
        }
    }
    s8v bq[4];
    #pragma unroll
    for (int s = 0; s < 4; ++s)
        bq[s] = *(const s8v*)&Pw[l31 * 72 + s * 16 + hi * 8];

    // ---- swizzled DMA staging: chunk c of row r -> LDS chunk c^(r&7)
    const int r8 = lane >> 3;                 // 0..7
    const int g8 = ((lane & 7) ^ r8) * 8;     // swizzled global elem offset
    auto stageK = [&](int kt, int buf) {
        const int k0e = kt * 64;
        const ush* kg = Kg + (size_t)(k0e + w * 16 + r8) * 64 + g8;
        gl_lds16(kg, &Kbuf[buf * 4096 + (w * 16) * 64]);
        gl_lds16(kg + 8 * 64, &Kbuf[buf * 4096 + (w * 16 + 8) * 64]);
    };
    auto stageV = [&](int kt, int buf) {
        const int k0e = kt * 64;
        const ush* vg = Vg + (size_t)(w * 16 + r8) * 2048 + k0e + g8;
        gl_lds16(vg, &Vbuf[buf * 4096 + (w * 16) * 64]);
        gl_lds16(vg + 8 * 2048, &Vbuf[buf * 4096 + (w * 16 + 8) * 64]);
    };

    f16v acco0 = {}, acco1 = {};
    float mr = -INFINITY, lr = 0.f;
    const int qg = q0 + w * 32 + l31;         // this lane's q row (global)

    // prologue: K0,V0 -> buf0; K1 -> buf1 (K runs 2 ahead, V 1 ahead)
    stageK(0, 0); stageV(0, 0); stageK(1, 1);
    __syncthreads();                           // drains all prologue DMA

    // S(0) from Kbuf[0]
    f16v s0 = {}, s1 = {};
    __builtin_amdgcn_s_setprio(1);
    #pragma unroll
    for (int s = 0; s < 4; ++s) {
        const int ch = (s << 1) + hi;                 // k-chunk 0..7
        const int row0 = l31, row1 = 32 + l31;
        s8v ak0 = *(const s8v*)&Kbuf[row0 * 64 + ((ch ^ (row0 & 7)) << 3)];
        s8v ak1 = *(const s8v*)&Kbuf[row1 * 64 + ((ch ^ (row1 & 7)) << 3)];
        s0 = __builtin_amdgcn_mfma_f32_32x32x16_bf16(ak0, bq[s], s0, 0, 0, 0);
        s1 = __builtin_amdgcn_mfma_f32_32x32x16_bf16(ak1, bq[s], s1, 0, 0, 0);
    }
    __builtin_amdgcn_s_setprio(0);
    // all waves must finish reading Kbuf[0] before body-0 DMAs K(2) into it
    __syncthreads();

    for (int kt = 0; kt <= ktmax; ++kt) {
        const int buf = kt & 1;

        // issue next-tile DMAs first (drained at this body's end barrier)
        if (kt < ktmax) {
            stageV(kt + 1, buf ^ 1);                  // V runs 1 ahead
            if (kt + 2 <= ktmax) stageK(kt + 2, buf); // K runs 2 ahead (dead slot)
        }

        // S(kt+1) from Kbuf[buf^1] — MFMA overlaps the softmax VALU below
        f16v t0 = {}, t1 = {};
        if (kt < ktmax) {
            __builtin_amdgcn_s_setprio(1);
            #pragma unroll
            for (int s = 0; s < 4; ++s) {
                const int ch = (s << 1) + hi;
                const int row0 = l31, row1 = 32 + l31;
                s8v ak0 = *(const s8v*)&Kbuf[(buf ^ 1) * 4096 + row0 * 64 + ((ch ^ (row0 & 7)) << 3)];
                s8v ak1 = *(const s8v*)&Kbuf[(buf ^ 1) * 4096 + row1 * 64 + ((ch ^ (row1 & 7)) << 3)];
                t0 = __builtin_amdgcn_mfma_f32_32x32x16_bf16(ak0, bq[s], t0, 0, 0, 0);
                t1 = __builtin_amdgcn_mfma_f32_32x32x16_bf16(ak1, bq[s], t1, 0, 0, 0);
            }
            __builtin_amdgcn_s_setprio(0);
        }

        // ---- softmax of S(kt) (s0/s1): mask (diag region only) + running max
        const bool needmask = (kt * 64 + 63) > (q0 + w * 32);
        float mloc = -INFINITY;
        #pragma unroll
        for (int r = 0; r < 16; ++r) {
            float v0 = s0[r], v1 = s1[r];
            if (needmask) {
                const int keyb = kt * 64 + (r & 3) + 8 * (r >> 2) + 4 * hi;
                if (keyb > qg) v0 = -INFINITY;
                if (keyb + 32 > qg) v1 = -INFINITY;
                s0[r] = v0; s1[r] = v1;
            }
            mloc = fmaxf(mloc, fmaxf(v0, v1));
        }
        mloc = fmaxf(mloc, __shfl_xor(mloc, 32));

        // defer-max: only rescale when wave-wide growth exceeds 2^8 (log2 dom.)
        if (__any(mloc > mr + 8.0f)) {
            const float mnew = fmaxf(mr, mloc);
            const float alpha = EXP2F(mr - mnew);   // kt=0: exp2(-inf)=0
            #pragma unroll
            for (int r = 0; r < 16; ++r) { acco0[r] *= alpha; acco1[r] *= alpha; }
            lr *= alpha;
            mr = mnew;
        }

        // exp2, sum, pack P -> LDS ([q][key], 4 consecutive keys per b64)
        float ps = 0.f;
        #pragma unroll
        for (int g4 = 0; g4 < 4; ++g4) {
            float e0a = EXP2F(s0[g4 * 4 + 0] - mr), e0b = EXP2F(s0[g4 * 4 + 1] - mr);
            float e0c = EXP2F(s0[g4 * 4 + 2] - mr), e0d = EXP2F(s0[g4 * 4 + 3] - mr);
            float e1a = EXP2F(s1[g4 * 4 + 0] - mr), e1b = EXP2F(s1[g4 * 4 + 1] - mr);
            float e1c = EXP2F(s1[g4 * 4 + 2] - mr), e1d = EXP2F(s1[g4 * 4 + 3] - mr);
            ps += (e0a + e0b) + (e0c + e0d) + (e1a + e1b) + (e1c + e1d);
            uint2 p0; p0.x = bfpack(e0a, e0b); p0.y = bfpack(e0c, e0d);
            uint2 p1; p1.x = bfpack(e1a, e1b); p1.y = bfpack(e1c, e1d);
            const int off = g4 * 8 + hi * 4;
            *(uint2*)&Pw[l31 * 72 + off] = p0;
            *(uint2*)&Pw[l31 * 72 + 32 + off] = p1;
        }
        ps += __shfl_xor(ps, 32);
        lr += ps;

        // O^T += V^T P^T : rows=d (2 tiles of 32), col=q
        __builtin_amdgcn_s_setprio(1);
        #pragma unroll
        for (int s = 0; s < 4; ++s) {
            s8v pf = *(const s8v*)&Pw[l31 * 72 + s * 16 + hi * 8];
            const int ch = (s << 1) + hi;
            const int row0 = l31, row1 = 32 + l31;
            s8v av0 = *(const s8v*)&Vbuf[buf * 4096 + row0 * 64 + ((ch ^ (row0 & 7)) << 3)];
            s8v av1 = *(const s8v*)&Vbuf[buf * 4096 + row1 * 64 + ((ch ^ (row1 & 7)) << 3)];
            acco0 = __builtin_amdgcn_mfma_f32_32x32x16_bf16(av0, pf, acco0, 0, 0, 0);
            acco1 = __builtin_amdgcn_mfma_f32_32x32x16_bf16(av1, pf, acco1, 0, 0, 0);
        }
        __builtin_amdgcn_s_setprio(0);

        __syncthreads();   // waves done with bufs; next-tile DMAs drained here
        s0 = t0; s1 = t1;  // rotate pipeline state
    }

    // ---- epilogue: LDS transpose (overlay K/V/P area) -> coalesced stores
    __syncthreads();
    float* LTw = (float*)SMEM + w * (32 * 68);
    const float inv = 1.0f / lr;
    #pragma unroll
    for (int r = 0; r < 16; ++r) {
        const int d = (r & 3) + 8 * (r >> 2) + 4 * hi;
        LTw[l31 * 68 + d] = acco0[r] * inv;
        LTw[l31 * 68 + 32 + d] = acco1[r] * inv;
    }
    // wave-private region; DS in-order. Read rows, store float4.
    const int qr4 = lane >> 4, chk = lane & 15;
    #pragma unroll
    for (int p = 0; p < 8; ++p) {
        const int qrow = p * 4 + qr4;
        f4v v = *(const f4v*)&LTw[qrow * 68 + chk * 4];
        *(float4*)(Y + (size_t)(b * 2048 + q0 + w * 32 + qrow) * 1024
                   + h * 64 + chk * 4) = (float4){v[0], v[1], v[2], v[3]};
    }
}

// ---------------------------------------------------------------------------
extern "C" void kernel_launch(void* const* d_in, const int* in_sizes, int n_in,
                              void* d_out, int out_size, void* d_ws,
                              size_t ws_size, hipStream_t stream)
{
    const float* x_qk = (const float*)d_in[0];
    const float* x_v  = (const float*)d_in[1];
    const float* W    = (const float*)d_in[2];
    const float* bias = (const float*)d_in[3];
    float* out = (float*)d_out;

    unsigned char* ws = (unsigned char*)d_ws;
    ush* Xb = (ush*)(ws);                  // 8 MB; dead after gemm
    ush* Vt = (ush*)(ws);                  // 8 MB; written after gemm
    ush* Wt = (ush*)(ws + (8u << 20));     // 4 MB
    ush* Qb = (ush*)(ws + (12u << 20));    // 8 MB
    ush* Kb = (ush*)(ws + (20u << 20));    // 8 MB (28 MB peak)

    prepA_kernel<<<2560, 256, 0, stream>>>(x_qk, W, Xb, Wt);
    gemm_kernel<<<dim3(16, 32), 256, 0, stream>>>(Xb, Wt, bias, Qb, Kb);
    vt_kernel<<<dim3(32, 32), 256, 0, stream>>>(x_v, Vt);
    attn_kernel<<<512, 256, 0, stream>>>(Qb, Kb, Vt, out);
}

// Round 2
// 165.744 us; speedup vs baseline: 1.0073x; 1.0073x over previous
//
#include <hip/hip_runtime.h>
#include <hip/hip_bf16.h>
#include <math.h>

// B=2, T=2048, C=1024, H=16, D=64
typedef __attribute__((ext_vector_type(8))) short s8v;    // 8 bf16
typedef __attribute__((ext_vector_type(4))) float f4v;    // 4 fp32
typedef __attribute__((ext_vector_type(16))) float f16v;  // 16 fp32 (32x32 C/D)
typedef unsigned short ush;
typedef unsigned int u32;

#define QSCALE 0.180336880f   /* 0.125 * log2(e): S emerges in log2 domain */
#define FIXED_M 10.0f         /* fixed softmax shift; |s|<=~15 whp, overflow-safe */

static __device__ __forceinline__ ush f2bf(float f) {
    u32 x = __builtin_bit_cast(u32, f);
    return (ush)((x + 0x7fffu + ((x >> 16) & 1u)) >> 16);
}
static __device__ __forceinline__ u32 bfpack(float lo, float hi) {
    u32 a = __builtin_bit_cast(u32, lo) + 0x8000u;
    u32 b = __builtin_bit_cast(u32, hi) + 0x8000u;
    return __builtin_amdgcn_perm(b, a, 0x07060302);
}
static __device__ __forceinline__ void gl_lds16(const void* g, void* l) {
    __builtin_amdgcn_global_load_lds(
        (const __attribute__((address_space(1))) u32*)g,
        (__attribute__((address_space(3))) u32*)l, 16, 0, 0);
}
#if __has_builtin(__builtin_amdgcn_exp2f)
#define EXP2F(x) __builtin_amdgcn_exp2f(x)
#else
#define EXP2F(x) exp2f(x)
#endif

// cross-block merge state (module globals: no hipMalloc, graph-capture safe)
__device__ int   flags_g[512];          // one per (bh, qt) pair
__device__ float lpart_g[512 * 128];    // writer's per-q-row l

// work-item table: 24 chunks per bh.
//  j0..7 : qt 8..14 lo(16t, merger) + qt15 lo(16t, writer)
//  j8..15: qt15 hi(16t, merger) / qt7 full ... interleaved descending size
//  role: 0=full, 1=part-writer, 2=part-merger
static __device__ const signed char qt_t[24]   = {8,9,10,11,12,13,14,15, 15,7, 14,6, 13,5, 12,4, 11,3, 10,2, 9,1, 8,0};
static __device__ const signed char kb_t[24]   = {0,0,0,0,0,0,0,0, 16,0, 16,0, 16,0, 16,0, 16,0, 16,0, 16,0, 16,0};
static __device__ const signed char kn_t[24]   = {16,16,16,16,16,16,16,16, 16,16, 14,14, 12,12, 10,10, 8,8, 6,6, 4,4, 2,2};
static __device__ const signed char role_t[24] = {2,2,2,2,2,2,2,1, 2,0, 1,0, 1,0, 1,0, 1,0, 1,0, 1,0, 1,0};

// ---------------------------------------------------------------------------
// Prep A (fused): blocks [0,2048): Xb = bf16(X); [2048,2560): Wt[n][k]=W[k][n]
// Also zeroes the merge flags for this iteration (blocks 0,1).
// ---------------------------------------------------------------------------
__global__ __launch_bounds__(256) void prepA_kernel(
    const float* __restrict__ X, const float* __restrict__ W,
    ush* __restrict__ Xb, ush* __restrict__ Wt)
{
    __shared__ float Ts[64][68];
    const int tid = threadIdx.x;
    const int bid = blockIdx.x;
    if (bid < 2) flags_g[bid * 256 + tid] = 0;
    if (bid < 2048) {
        const size_t i = ((size_t)bid * 256 + tid) * 8;
        float4 v0 = *(const float4*)(X + i);
        float4 v1 = *(const float4*)(X + i + 4);
        uint4 o;
        o.x = bfpack(v0.x, v0.y); o.y = bfpack(v0.z, v0.w);
        o.z = bfpack(v1.x, v1.y); o.w = bfpack(v1.z, v1.w);
        *(uint4*)(Xb + i) = o;
    } else {
        const int id = bid - 2048;           // 512 blocks: 32 x 16
        const int n0 = (id & 31) * 64, k0 = (id >> 5) * 64;
        #pragma unroll
        for (int p = 0; p < 4; ++p) {
            const int idx = p * 256 + tid;
            const int kr = idx >> 4, nc4 = idx & 15;
            float4 v = *(const float4*)(W + (size_t)(k0 + kr) * 2048 + n0 + nc4 * 4);
            Ts[kr][nc4 * 4 + 0] = v.x; Ts[kr][nc4 * 4 + 1] = v.y;
            Ts[kr][nc4 * 4 + 2] = v.z; Ts[kr][nc4 * 4 + 3] = v.w;
        }
        __syncthreads();
        const int n = tid >> 2, kb = (tid & 3) * 16;
        #pragma unroll
        for (int p = 0; p < 4; ++p) {
            const int k = kb + p * 4;
            ushort4 o;
            o.x = f2bf(Ts[k + 0][n]); o.y = f2bf(Ts[k + 1][n]);
            o.z = f2bf(Ts[k + 2][n]); o.w = f2bf(Ts[k + 3][n]);
            *(ushort4*)(Wt + (size_t)(n0 + n) * 1024 + k0 + k) = o;
        }
    }
}

// ---------------------------------------------------------------------------
// Prep B: Vt[b][h][d][t] = bf16(x_v[b][t][h*64+d]).  grid (32, 32).
// ---------------------------------------------------------------------------
__global__ __launch_bounds__(256) void vt_kernel(
    const float* __restrict__ XV, ush* __restrict__ Vt)
{
    __shared__ float Ts[64][68];
    const int tid = threadIdx.x;
    const int t0 = blockIdx.x * 64;
    const int bh = blockIdx.y;
    const int b = bh >> 4, h = bh & 15;
    #pragma unroll
    for (int p = 0; p < 4; ++p) {
        const int idx = p * 256 + tid;
        const int tr = idx >> 4, dc4 = idx & 15;
        float4 v = *(const float4*)(XV + (size_t)(b * 2048 + t0 + tr) * 1024
                                    + h * 64 + dc4 * 4);
        Ts[tr][dc4 * 4 + 0] = v.x; Ts[tr][dc4 * 4 + 1] = v.y;
        Ts[tr][dc4 * 4 + 2] = v.z; Ts[tr][dc4 * 4 + 3] = v.w;
    }
    __syncthreads();
    const int d = tid >> 2, tb = (tid & 3) * 16;
    #pragma unroll
    for (int p = 0; p < 4; ++p) {
        const int tq = tb + p * 4;
        ushort4 o;
        o.x = f2bf(Ts[tq + 0][d]); o.y = f2bf(Ts[tq + 1][d]);
        o.z = f2bf(Ts[tq + 2][d]); o.w = f2bf(Ts[tq + 3][d]);
        *(ushort4*)(Vt + (size_t)((b * 16 + h) * 64 + d) * 2048 + t0 + tq) = o;
    }
}

// ---------------------------------------------------------------------------
// MFMA GEMM (m97 structure): C = Xb @ Wt^T + bias; Q scaled by 0.125*log2e.
// ---------------------------------------------------------------------------
__global__ __launch_bounds__(256) void gemm_kernel(
    const ush* __restrict__ Xb, const ush* __restrict__ Wt,
    const float* __restrict__ bias,
    ush* __restrict__ Qb, ush* __restrict__ Kb)
{
    __shared__ ush As[128 * 32];
    __shared__ ush Bs[128 * 32];

    const int tid = threadIdx.x;
    const int wid = tid >> 6, lane = tid & 63;
    const int quad = lane >> 4, l15 = lane & 15;
    const int wm = wid >> 1, wn = wid & 1;
    const int m0 = blockIdx.y * 128, n0 = blockIdx.x * 128;

    const int lrow = lane >> 2;
    const int lkk = (lane & 3) * 8;
    const size_t arow = (size_t)(m0 + wid * 32 + lrow);
    const size_t brow = (size_t)(n0 + wid * 32 + lrow);
    ush* AsW = &As[wid * 1024];
    ush* BsW = &Bs[wid * 1024];

    f4v acc[4][4];
    #pragma unroll
    for (int i = 0; i < 4; ++i)
        #pragma unroll
        for (int j = 0; j < 4; ++j) acc[i][j] = (f4v){0.f, 0.f, 0.f, 0.f};

    for (int k0 = 0; k0 < 1024; k0 += 32) {
        gl_lds16(Xb + arow * 1024 + k0 + lkk, AsW);
        gl_lds16(Xb + (arow + 16) * 1024 + k0 + lkk, AsW + 512);
        gl_lds16(Wt + brow * 1024 + k0 + lkk, BsW);
        gl_lds16(Wt + (brow + 16) * 1024 + k0 + lkk, BsW + 512);
        __syncthreads();

        s8v a[4], bf[4];
        #pragma unroll
        for (int i = 0; i < 4; ++i)
            a[i] = *(const s8v*)&As[(wm * 64 + i * 16 + l15) * 32 + quad * 8];
        #pragma unroll
        for (int j = 0; j < 4; ++j)
            bf[j] = *(const s8v*)&Bs[(wn * 64 + j * 16 + l15) * 32 + quad * 8];
        #pragma unroll
        for (int i = 0; i < 4; ++i)
            #pragma unroll
            for (int j = 0; j < 4; ++j)
                acc[i][j] = __builtin_amdgcn_mfma_f32_16x16x32_bf16(
                    a[i], bf[j], acc[i][j], 0, 0, 0);
        __syncthreads();
    }

    #pragma unroll
    for (int j = 0; j < 4; ++j) {
        const int n = n0 + wn * 64 + j * 16 + l15;
        const float bv = bias[n];
        const bool is_k = n >= 1024;
        const int nn = n & 1023;
        const int h = nn >> 6, d = nn & 63;
        ush* dst = is_k ? Kb : Qb;
        #pragma unroll
        for (int i = 0; i < 4; ++i) {
            const int mrow = m0 + wm * 64 + i * 16 + quad * 4;
            #pragma unroll
            for (int r = 0; r < 4; ++r) {
                const int m = mrow + r;
                const int b = m >> 11, t = m & 2047;
                float val = acc[i][j][r] + bv;
                if (!is_k) val *= QSCALE;
                dst[(size_t)((b * 16 + h) * 2048 + t) * 64 + d] = f2bf(val);
            }
        }
    }
}

// ---------------------------------------------------------------------------
// MFMA causal flash attention, 32x32x16, S^T form.
//   v3: key-split decomposition. 768 blocks (24 chunks/bh): qt>=8 rows split
//   into lo(16 k-tiles, maskless) + hi(rest, diagonal) chunks; partials merged
//   in-kernel (shorter chunk writes unnormalized O->Y + l, sets release flag;
//   longer chunk merges — poll is ~free since it has >= the work). 3 blocks/CU
//   (LDS 51.7KB, launch_bounds(256,3)) => all 768 resident: no dispatch-order
//   assumption for the poll. Fixed-M softmax (p = exp2(s-10), exact after
//   normalization since scores bounded) deletes max-reduce/rescale from the
//   per-tile chain and makes O,l pure sums (order-free merge).
// ---------------------------------------------------------------------------
__global__ __launch_bounds__(256, 3) void attn_kernel(
    const ush* __restrict__ Qb, const ush* __restrict__ Kb,
    const ush* __restrict__ Vt, float* __restrict__ Y)
{
    // SMEM carve: Kbuf 2x4096, Vbuf 2x4096, Pq 4x(32*72)  (51200 B) + Lw
    __shared__ ush SMEM[25600];
    __shared__ float Lw[4][32];
    ush* Kbuf = SMEM;                 // [buf*4096 + row*64 + elem]
    ush* Vbuf = SMEM + 8192;
    ush* Pq   = SMEM + 16384;        // + w*2304

    const int tid = threadIdx.x;
    const int w = tid >> 6, lane = tid & 63;
    const int l31 = lane & 31, hi = lane >> 5;     // hi in {0,1}

    // block -> work item; j-permutation balances per-CU tile sums (34 each)
    const int idx = blockIdx.x;
    const int g = idx >> 8, c = idx & 255;
    const int x = c >> 5, bh = c & 31;
    const int j = (g == 0) ? x : (g == 1 ? (15 - x) : (16 + x));
    const int qt = qt_t[j], kb = kb_t[j], kn = kn_t[j], role = role_t[j];
    const int b = bh >> 4, h = bh & 15;
    const int q0 = qt * 128;

    const ush* Qg = Qb + (size_t)bh * 2048 * 64;
    const ush* Kg = Kb + (size_t)bh * 2048 * 64;
    const ush* Vg = Vt + (size_t)bh * 64 * 2048;

    ush* Pw = Pq + w * 2304;

    // ---- stage Q rows (wave-private) and pull B-frags into regs
    {
        const int r8q = lane >> 3, c8 = lane & 7;
        #pragma unroll
        for (int p = 0; p < 4; ++p) {
            const int row = p * 8 + r8q;
            uint4 v = *(const uint4*)(Qg + (size_t)(q0 + w * 32 + row) * 64 + c8 * 8);
            *(uint4*)&Pw[row * 72 + c8 * 8] = v;
        }
    }
    s8v bq[4];
    #pragma unroll
    for (int s = 0; s < 4; ++s)
        bq[s] = *(const s8v*)&Pw[l31 * 72 + s * 16 + hi * 8];

    // ---- swizzled DMA staging: chunk c of row r -> LDS chunk c^(r&7)
    const int r8 = lane >> 3;                 // 0..7
    const int g8 = ((lane & 7) ^ r8) * 8;     // swizzled global elem offset
    auto stage = [&](int kt, int buf) {
        const int k0e = kt * 64;
        const ush* kg = Kg + (size_t)(k0e + w * 16 + r8) * 64 + g8;
        gl_lds16(kg, &Kbuf[buf * 4096 + (w * 16) * 64]);
        gl_lds16(kg + 8 * 64, &Kbuf[buf * 4096 + (w * 16 + 8) * 64]);
        const ush* vg = Vg + (size_t)(w * 16 + r8) * 2048 + k0e + g8;
        gl_lds16(vg, &Vbuf[buf * 4096 + (w * 16) * 64]);
        gl_lds16(vg + 8 * 2048, &Vbuf[buf * 4096 + (w * 16 + 8) * 64]);
    };

    f16v acco0 = {}, acco1 = {};
    float lr = 0.f;
    const int qg = q0 + w * 32 + l31;         // this lane's q row (global)

    stage(kb, 0);
    __syncthreads();                           // drains DMA (vmcnt before barrier)

    for (int i = 0; i < kn; ++i) {
        const int kt = kb + i;
        const int buf = i & 1;
        if (i + 1 < kn) stage(kt + 1, buf ^ 1);

        // S^T = K Q^T: rows=keys (2 tiles of 32), col=q=l31
        f16v s0 = {}, s1 = {};
        #pragma unroll
        for (int s = 0; s < 4; ++s) {
            const int ch = (s << 1) + hi;                 // k-chunk 0..7
            const int row0 = l31, row1 = 32 + l31;
            s8v ak0 = *(const s8v*)&Kbuf[buf * 4096 + row0 * 64 + ((ch ^ (row0 & 7)) << 3)];
            s8v ak1 = *(const s8v*)&Kbuf[buf * 4096 + row1 * 64 + ((ch ^ (row1 & 7)) << 3)];
            s0 = __builtin_amdgcn_mfma_f32_32x32x16_bf16(ak0, bq[s], s0, 0, 0, 0);
            s1 = __builtin_amdgcn_mfma_f32_32x32x16_bf16(ak1, bq[s], s1, 0, 0, 0);
        }

        // causal mask — only tiles touching the diagonal (never for lo chunks)
        if ((kt * 64 + 63) > (q0 + w * 32)) {
            #pragma unroll
            for (int r = 0; r < 16; ++r) {
                const int keyb = kt * 64 + (r & 3) + 8 * (r >> 2) + 4 * hi;
                if (keyb > qg) s0[r] = -INFINITY;
                if (keyb + 32 > qg) s1[r] = -INFINITY;
            }
        }

        // fixed-M exp2, sum, pack P -> LDS ([q][key], 4 consecutive per b64)
        float ps = 0.f;
        #pragma unroll
        for (int g4 = 0; g4 < 4; ++g4) {
            float e0a = EXP2F(s0[g4 * 4 + 0] - FIXED_M), e0b = EXP2F(s0[g4 * 4 + 1] - FIXED_M);
            float e0c = EXP2F(s0[g4 * 4 + 2] - FIXED_M), e0d = EXP2F(s0[g4 * 4 + 3] - FIXED_M);
            float e1a = EXP2F(s1[g4 * 4 + 0] - FIXED_M), e1b = EXP2F(s1[g4 * 4 + 1] - FIXED_M);
            float e1c = EXP2F(s1[g4 * 4 + 2] - FIXED_M), e1d = EXP2F(s1[g4 * 4 + 3] - FIXED_M);
            ps += (e0a + e0b) + (e0c + e0d) + (e1a + e1b) + (e1c + e1d);
            uint2 p0; p0.x = bfpack(e0a, e0b); p0.y = bfpack(e0c, e0d);
            uint2 p1; p1.x = bfpack(e1a, e1b); p1.y = bfpack(e1c, e1d);
            const int off = g4 * 8 + hi * 4;
            *(uint2*)&Pw[l31 * 72 + off] = p0;
            *(uint2*)&Pw[l31 * 72 + 32 + off] = p1;
        }
        ps += __shfl_xor(ps, 32);
        lr += ps;

        // O^T += V^T P^T : rows=d (2 tiles of 32), col=q
        #pragma unroll
        for (int s = 0; s < 4; ++s) {
            s8v pf = *(const s8v*)&Pw[l31 * 72 + s * 16 + hi * 8];
            const int ch = (s << 1) + hi;
            const int row0 = l31, row1 = 32 + l31;
            s8v av0 = *(const s8v*)&Vbuf[buf * 4096 + row0 * 64 + ((ch ^ (row0 & 7)) << 3)];
            s8v av1 = *(const s8v*)&Vbuf[buf * 4096 + row1 * 64 + ((ch ^ (row1 & 7)) << 3)];
            acco0 = __builtin_amdgcn_mfma_f32_32x32x16_bf16(av0, pf, acco0, 0, 0, 0);
            acco1 = __builtin_amdgcn_mfma_f32_32x32x16_bf16(av1, pf, acco1, 0, 0, 0);
        }

        __syncthreads();   // waves done with buf; DMAs for buf^1 drained here
    }

    // ---- epilogue: LDS transpose (overlay K/V/P area) -> coalesced path
    __syncthreads();
    float* LTw = (float*)SMEM + w * (32 * 68);
    if (hi == 0) Lw[w][l31] = lr;              // wave-private, DS in-order
    #pragma unroll
    for (int r = 0; r < 16; ++r) {
        const int d = (r & 3) + 8 * (r >> 2) + 4 * hi;
        LTw[l31 * 68 + d] = acco0[r];
        LTw[l31 * 68 + 32 + d] = acco1[r];
    }
    const int qr4 = lane >> 4, chk = lane & 15;
    const int pair = bh * 16 + qt;

    if (role == 2) {                            // merger: wait for writer
        if (tid == 0) {
            while (__hip_atomic_load(&flags_g[pair], __ATOMIC_ACQUIRE,
                                     __HIP_MEMORY_SCOPE_AGENT) == 0)
                __builtin_amdgcn_s_sleep(8);
        }
        __syncthreads();
    }

    #pragma unroll
    for (int p = 0; p < 8; ++p) {
        const int qrow = p * 4 + qr4;
        f4v v = *(const f4v*)&LTw[qrow * 68 + chk * 4];
        const float lme = Lw[w][qrow];
        float* yp = Y + (size_t)(b * 2048 + q0 + w * 32 + qrow) * 1024
                    + h * 64 + chk * 4;
        if (role == 0) {
            const float inv = 1.0f / lme;
            *(float4*)yp = (float4){v[0] * inv, v[1] * inv, v[2] * inv, v[3] * inv};
        } else if (role == 1) {
            *(float4*)yp = (float4){v[0], v[1], v[2], v[3]};
            if (chk == 0) lpart_g[pair * 128 + w * 32 + qrow] = lme;
        } else {
            const float4 pv = *(const float4*)yp;
            const float lp = lpart_g[pair * 128 + w * 32 + qrow];
            const float inv = 1.0f / (lme + lp);
            *(float4*)yp = (float4){(v[0] + pv.x) * inv, (v[1] + pv.y) * inv,
                                    (v[2] + pv.z) * inv, (v[3] + pv.w) * inv};
        }
    }

    if (role == 1) {                            // publish partial
        __syncthreads();                        // all stores complete (vmcnt0)
        if (tid == 0) {
            __threadfence();                    // device-scope writeback
            __hip_atomic_store(&flags_g[pair], 1, __ATOMIC_RELEASE,
                               __HIP_MEMORY_SCOPE_AGENT);
        }
    }
}

// ---------------------------------------------------------------------------
extern "C" void kernel_launch(void* const* d_in, const int* in_sizes, int n_in,
                              void* d_out, int out_size, void* d_ws,
                              size_t ws_size, hipStream_t stream)
{
    const float* x_qk = (const float*)d_in[0];
    const float* x_v  = (const float*)d_in[1];
    const float* W    = (const float*)d_in[2];
    const float* bias = (const float*)d_in[3];
    float* out = (float*)d_out;

    unsigned char* ws = (unsigned char*)d_ws;
    ush* Xb = (ush*)(ws);                  // 8 MB; dead after gemm
    ush* Vt = (ush*)(ws);                  // 8 MB; written after gemm
    ush* Wt = (ush*)(ws + (8u << 20));     // 4 MB
    ush* Qb = (ush*)(ws + (12u << 20));    // 8 MB
    ush* Kb = (ush*)(ws + (20u << 20));    // 8 MB (28 MB peak)

    prepA_kernel<<<2560, 256, 0, stream>>>(x_qk, W, Xb, Wt);
    gemm_kernel<<<dim3(16, 32), 256, 0, stream>>>(Xb, Wt, bias, Qb, Kb);
    vt_kernel<<<dim3(32, 32), 256, 0, stream>>>(x_v, Vt);
    attn_kernel<<<768, 256, 0, stream>>>(Qb, Kb, Vt, out);
}

// Round 4
// 151.102 us; speedup vs baseline: 1.1049x; 1.0969x over previous
//
#include <hip/hip_runtime.h>
#include <hip/hip_bf16.h>
#include <math.h>

// B=2, T=2048, C=1024, H=16, D=64
typedef __attribute__((ext_vector_type(8))) short s8v;    // 8 bf16
typedef __attribute__((ext_vector_type(4))) float f4v;    // 4 fp32
typedef __attribute__((ext_vector_type(16))) float f16v;  // 16 fp32 (32x32 C/D)
typedef __attribute__((ext_vector_type(2))) unsigned int u32x2;
typedef unsigned short ush;
typedef unsigned int u32;

#define QSCALE 0.180336880f   /* 0.125 * log2(e): S emerges in log2 domain */
#define FIXED_M 10.0f         /* fixed softmax shift; scores bounded, exact after norm */

static __device__ __forceinline__ ush f2bf(float f) {
    u32 x = __builtin_bit_cast(u32, f);
    return (ush)((x + 0x7fffu + ((x >> 16) & 1u)) >> 16);
}
static __device__ __forceinline__ u32 bfpack(float lo, float hi) {
    u32 a = __builtin_bit_cast(u32, lo) + 0x8000u;
    u32 b = __builtin_bit_cast(u32, hi) + 0x8000u;
    return __builtin_amdgcn_perm(b, a, 0x07060302);
}
static __device__ __forceinline__ void gl_lds16(const void* g, void* l) {
    __builtin_amdgcn_global_load_lds(
        (const __attribute__((address_space(1))) u32*)g,
        (__attribute__((address_space(3))) u32*)l, 16, 0, 0);
}
#if __has_builtin(__builtin_amdgcn_exp2f)
#define EXP2F(x) __builtin_amdgcn_exp2f(x)
#else
#define EXP2F(x) exp2f(x)
#endif

// D.hi <-> S.lo lane swap (v_permlane32_swap_b32): after call,
//   a[l<32]=a_old, a[l>=32]=b_old[l-32]; b[l<32]=a_old[l+32], b[l>=32]=b_old.
static __device__ __forceinline__ void pl32swap(u32& a, u32& b) {
#if __has_builtin(__builtin_amdgcn_permlane32_swap)
    u32x2 r = __builtin_amdgcn_permlane32_swap(a, b, false, false);
    a = r[0]; b = r[1];
#else
    asm volatile("v_permlane32_swap_b32 %0, %1" : "+v"(a), "+v"(b));
#endif
}
static __device__ __forceinline__ s8v mkfrag(u32 a, u32 b, u32 c, u32 d) {
    union { u32 w[4]; s8v v; } u;
    u.w[0] = a; u.w[1] = b; u.w[2] = c; u.w[3] = d;
    return u.v;
}

// ---------------------------------------------------------------------------
// Prep A (fused): blocks [0,2048): Xb = bf16(X); [2048,2560): Wt[n][k]=W[k][n]
// ---------------------------------------------------------------------------
__global__ __launch_bounds__(256) void prepA_kernel(
    const float* __restrict__ X, const float* __restrict__ W,
    ush* __restrict__ Xb, ush* __restrict__ Wt)
{
    __shared__ float Ts[64][68];
    const int tid = threadIdx.x;
    const int bid = blockIdx.x;
    if (bid < 2048) {
        const size_t i = ((size_t)bid * 256 + tid) * 8;
        float4 v0 = *(const float4*)(X + i);
        float4 v1 = *(const float4*)(X + i + 4);
        uint4 o;
        o.x = bfpack(v0.x, v0.y); o.y = bfpack(v0.z, v0.w);
        o.z = bfpack(v1.x, v1.y); o.w = bfpack(v1.z, v1.w);
        *(uint4*)(Xb + i) = o;
    } else {
        const int id = bid - 2048;           // 512 blocks: 32 x 16
        const int n0 = (id & 31) * 64, k0 = (id >> 5) * 64;
        #pragma unroll
        for (int p = 0; p < 4; ++p) {
            const int idx = p * 256 + tid;
            const int kr = idx >> 4, nc4 = idx & 15;
            float4 v = *(const float4*)(W + (size_t)(k0 + kr) * 2048 + n0 + nc4 * 4);
            Ts[kr][nc4 * 4 + 0] = v.x; Ts[kr][nc4 * 4 + 1] = v.y;
            Ts[kr][nc4 * 4 + 2] = v.z; Ts[kr][nc4 * 4 + 3] = v.w;
        }
        __syncthreads();
        const int n = tid >> 2, kb = (tid & 3) * 16;
        #pragma unroll
        for (int p = 0; p < 4; ++p) {
            const int k = kb + p * 4;
            ushort4 o;
            o.x = f2bf(Ts[k + 0][n]); o.y = f2bf(Ts[k + 1][n]);
            o.z = f2bf(Ts[k + 2][n]); o.w = f2bf(Ts[k + 3][n]);
            *(ushort4*)(Wt + (size_t)(n0 + n) * 1024 + k0 + k) = o;
        }
    }
}

// ---------------------------------------------------------------------------
// Prep B: Vt[b][h][d][t] = bf16(x_v[b][t][h*64+d]).  grid (32, 32).
// ---------------------------------------------------------------------------
__global__ __launch_bounds__(256) void vt_kernel(
    const float* __restrict__ XV, ush* __restrict__ Vt)
{
    __shared__ float Ts[64][68];
    const int tid = threadIdx.x;
    const int t0 = blockIdx.x * 64;
    const int bh = blockIdx.y;
    const int b = bh >> 4, h = bh & 15;
    #pragma unroll
    for (int p = 0; p < 4; ++p) {
        const int idx = p * 256 + tid;
        const int tr = idx >> 4, dc4 = idx & 15;
        float4 v = *(const float4*)(XV + (size_t)(b * 2048 + t0 + tr) * 1024
                                    + h * 64 + dc4 * 4);
        Ts[tr][dc4 * 4 + 0] = v.x; Ts[tr][dc4 * 4 + 1] = v.y;
        Ts[tr][dc4 * 4 + 2] = v.z; Ts[tr][dc4 * 4 + 3] = v.w;
    }
    __syncthreads();
    const int d = tid >> 2, tb = (tid & 3) * 16;
    #pragma unroll
    for (int p = 0; p < 4; ++p) {
        const int tq = tb + p * 4;
        ushort4 o;
        o.x = f2bf(Ts[tq + 0][d]); o.y = f2bf(Ts[tq + 1][d]);
        o.z = f2bf(Ts[tq + 2][d]); o.w = f2bf(Ts[tq + 3][d]);
        *(ushort4*)(Vt + (size_t)((b * 16 + h) * 64 + d) * 2048 + t0 + tq) = o;
    }
}

// ---------------------------------------------------------------------------
// MFMA GEMM (m97 structure): C = Xb @ Wt^T + bias; Q scaled by 0.125*log2e.
// ---------------------------------------------------------------------------
__global__ __launch_bounds__(256) void gemm_kernel(
    const ush* __restrict__ Xb, const ush* __restrict__ Wt,
    const float* __restrict__ bias,
    ush* __restrict__ Qb, ush* __restrict__ Kb)
{
    __shared__ ush As[128 * 32];
    __shared__ ush Bs[128 * 32];

    const int tid = threadIdx.x;
    const int wid = tid >> 6, lane = tid & 63;
    const int quad = lane >> 4, l15 = lane & 15;
    const int wm = wid >> 1, wn = wid & 1;
    const int m0 = blockIdx.y * 128, n0 = blockIdx.x * 128;

    const int lrow = lane >> 2;
    const int lkk = (lane & 3) * 8;
    const size_t arow = (size_t)(m0 + wid * 32 + lrow);
    const size_t brow = (size_t)(n0 + wid * 32 + lrow);
    ush* AsW = &As[wid * 1024];
    ush* BsW = &Bs[wid * 1024];

    f4v acc[4][4];
    #pragma unroll
    for (int i = 0; i < 4; ++i)
        #pragma unroll
        for (int j = 0; j < 4; ++j) acc[i][j] = (f4v){0.f, 0.f, 0.f, 0.f};

    for (int k0 = 0; k0 < 1024; k0 += 32) {
        gl_lds16(Xb + arow * 1024 + k0 + lkk, AsW);
        gl_lds16(Xb + (arow + 16) * 1024 + k0 + lkk, AsW + 512);
        gl_lds16(Wt + brow * 1024 + k0 + lkk, BsW);
        gl_lds16(Wt + (brow + 16) * 1024 + k0 + lkk, BsW + 512);
        __syncthreads();

        s8v a[4], bf[4];
        #pragma unroll
        for (int i = 0; i < 4; ++i)
            a[i] = *(const s8v*)&As[(wm * 64 + i * 16 + l15) * 32 + quad * 8];
        #pragma unroll
        for (int j = 0; j < 4; ++j)
            bf[j] = *(const s8v*)&Bs[(wn * 64 + j * 16 + l15) * 32 + quad * 8];
        #pragma unroll
        for (int i = 0; i < 4; ++i)
            #pragma unroll
            for (int j = 0; j < 4; ++j)
                acc[i][j] = __builtin_amdgcn_mfma_f32_16x16x32_bf16(
                    a[i], bf[j], acc[i][j], 0, 0, 0);
        __syncthreads();
    }

    #pragma unroll
    for (int j = 0; j < 4; ++j) {
        const int n = n0 + wn * 64 + j * 16 + l15;
        const float bv = bias[n];
        const bool is_k = n >= 1024;
        const int nn = n & 1023;
        const int h = nn >> 6, d = nn & 63;
        ush* dst = is_k ? Kb : Qb;
        #pragma unroll
        for (int i = 0; i < 4; ++i) {
            const int mrow = m0 + wm * 64 + i * 16 + quad * 4;
            #pragma unroll
            for (int r = 0; r < 4; ++r) {
                const int m = mrow + r;
                const int b = m >> 11, t = m & 2047;
                float val = acc[i][j][r] + bv;
                if (!is_k) val *= QSCALE;
                dst[(size_t)((b * 16 + h) * 2048 + t) * 64 + d] = f2bf(val);
            }
        }
    }
}

// ---------------------------------------------------------------------------
// MFMA causal flash attention, 32x32x16, S^T form, 128 q-rows per block.
//   v4 = round-0 structure + chain cuts:
//   - fixed-M softmax (p = exp2(s-10); exact after normalization): no max
//     pass, no shfl-max, no alpha rescale; mask fused into the exp pass.
//   - P never touches LDS: 16 bfpack + 8 v_permlane32_swap build the PV
//     B-fragments in-register (hi<->lo half exchange, same q per lane pair).
//   - all K/V ds_reads for tile kt issue BEFORE stage(kt+1)'s DMAs
//     (sched_barrier pins order) => no alias-conservative vmcnt stall can
//     sit inside the tile body.
//   - wave-uniform skip of fully-masked tiles (waves 0,1 save one tile).
// ---------------------------------------------------------------------------
__global__ __launch_bounds__(256, 2) void attn_kernel(
    const ush* __restrict__ Qb, const ush* __restrict__ Kb,
    const ush* __restrict__ Vt, float* __restrict__ Y)
{
    // SMEM carve: Kbuf 2x4096, Vbuf 2x4096, Pq 4x(32*72)  (51200 B total)
    __shared__ ush SMEM[25600];
    ush* Kbuf = SMEM;                 // [buf*4096 + row*64 + elem]
    ush* Vbuf = SMEM + 8192;
    ush* Pq   = SMEM + 16384;        // + w*2304 (Q staging + epilogue only)

    const int tid = threadIdx.x;
    const int w = tid >> 6, lane = tid & 63;
    const int l31 = lane & 31, hi = lane >> 5;     // hi in {0,1}

    // block mapping: CU gets blocks i and i+256 with qt summing to 15
    const int idx = blockIdx.x;
    const int half = idx >> 8, pair = idx & 255;
    const int qt = half ? (pair & 15) : 15 - (pair & 15);
    const int bh = (pair >> 4) + half * 16;
    const int b = bh >> 4, h = bh & 15;
    const int q0 = qt * 128;
    const int ktmax = 2 * qt + 1;

    const ush* Qg = Qb + (size_t)bh * 2048 * 64;
    const ush* Kg = Kb + (size_t)bh * 2048 * 64;
    const ush* Vg = Vt + (size_t)bh * 64 * 2048;

    ush* Pw = Pq + w * 2304;

    // ---- stage Q rows (wave-private) and pull B-frags into regs
    {
        const int r8q = lane >> 3, c8 = lane & 7;
        #pragma unroll
        for (int p = 0; p < 4; ++p) {
            const int row = p * 8 + r8q;
            uint4 v = *(const uint4*)(Qg + (size_t)(q0 + w * 32 + row) * 64 + c8 * 8);
            *(uint4*)&Pw[row * 72 + c8 * 8] = v;
        }
    }
    s8v bq[4];
    #pragma unroll
    for (int s = 0; s < 4; ++s)
        bq[s] = *(const s8v*)&Pw[l31 * 72 + s * 16 + hi * 8];

    // ---- swizzled DMA staging: chunk c of row r -> LDS chunk c^(r&7)
    const int r8 = lane >> 3;                 // 0..7
    const int g8 = ((lane & 7) ^ r8) * 8;     // swizzled global elem offset
    auto stage = [&](int kt, int buf) {
        const int k0e = kt * 64;
        const ush* kg = Kg + (size_t)(k0e + w * 16 + r8) * 64 + g8;
        gl_lds16(kg, &Kbuf[buf * 4096 + (w * 16) * 64]);
        gl_lds16(kg + 8 * 64, &Kbuf[buf * 4096 + (w * 16 + 8) * 64]);
        const ush* vg = Vg + (size_t)(w * 16 + r8) * 2048 + k0e + g8;
        gl_lds16(vg, &Vbuf[buf * 4096 + (w * 16) * 64]);
        gl_lds16(vg + 8 * 2048, &Vbuf[buf * 4096 + (w * 16 + 8) * 64]);
    };

    f16v acco0 = {}, acco1 = {};
    float lr = 0.f;
    const int qg = q0 + w * 32 + l31;         // this lane's q row (global)
    const int qwmax = q0 + w * 32 + 31;       // wave's last q row

    stage(0, 0);
    __syncthreads();                           // drains DMA (vmcnt before barrier)

    for (int kt = 0; kt <= ktmax; ++kt) {
        const int buf = kt & 1;
        const bool active = (kt * 64) <= qwmax;   // wave-uniform

        // ---- all LDS reads for this tile -> registers (before any DMA issue)
        s8v ak0[4], ak1[4], av0[4], av1[4];
        if (active) {
            #pragma unroll
            for (int s = 0; s < 4; ++s) {
                const int ch = (s << 1) + hi;             // chunk 0..7
                const int row0 = l31, row1 = 32 + l31;
                ak0[s] = *(const s8v*)&Kbuf[buf * 4096 + row0 * 64 + ((ch ^ (row0 & 7)) << 3)];
                ak1[s] = *(const s8v*)&Kbuf[buf * 4096 + row1 * 64 + ((ch ^ (row1 & 7)) << 3)];
                av0[s] = *(const s8v*)&Vbuf[buf * 4096 + row0 * 64 + ((ch ^ (row0 & 7)) << 3)];
                av1[s] = *(const s8v*)&Vbuf[buf * 4096 + row1 * 64 + ((ch ^ (row1 & 7)) << 3)];
            }
        }
        __builtin_amdgcn_sched_barrier(0);     // reads must precede DMA issue

        if (kt < ktmax) stage(kt + 1, buf ^ 1);

        if (active) {
            // S^T = K Q^T: rows=keys (2 tiles of 32), col=q=l31
            f16v s0 = {}, s1 = {};
            #pragma unroll
            for (int s = 0; s < 4; ++s) {
                s0 = __builtin_amdgcn_mfma_f32_32x32x16_bf16(ak0[s], bq[s], s0, 0, 0, 0);
                s1 = __builtin_amdgcn_mfma_f32_32x32x16_bf16(ak1[s], bq[s], s1, 0, 0, 0);
            }

            // fused mask + fixed-M exp2 + sum + pack (keys 8g+4hi+{0..3})
            float ps = 0.f;
            u32 w0[4], w1[4], x0[4], x1[4];
            const bool needmask = (kt * 64 + 63) > (q0 + w * 32);
            if (needmask) {
                const int kbase = kt * 64 + 4 * hi;
                #pragma unroll
                for (int g4 = 0; g4 < 4; ++g4) {
                    const int kb0 = kbase + 8 * g4;
                    float e0a = (kb0 + 0 > qg) ? 0.f : EXP2F(s0[g4 * 4 + 0] - FIXED_M);
                    float e0b = (kb0 + 1 > qg) ? 0.f : EXP2F(s0[g4 * 4 + 1] - FIXED_M);
                    float e0c = (kb0 + 2 > qg) ? 0.f : EXP2F(s0[g4 * 4 + 2] - FIXED_M);
                    float e0d = (kb0 + 3 > qg) ? 0.f : EXP2F(s0[g4 * 4 + 3] - FIXED_M);
                    float e1a = (kb0 + 32 > qg) ? 0.f : EXP2F(s1[g4 * 4 + 0] - FIXED_M);
                    float e1b = (kb0 + 33 > qg) ? 0.f : EXP2F(s1[g4 * 4 + 1] - FIXED_M);
                    float e1c = (kb0 + 34 > qg) ? 0.f : EXP2F(s1[g4 * 4 + 2] - FIXED_M);
                    float e1d = (kb0 + 35 > qg) ? 0.f : EXP2F(s1[g4 * 4 + 3] - FIXED_M);
                    ps += (e0a + e0b) + (e0c + e0d) + (e1a + e1b) + (e1c + e1d);
                    w0[g4] = bfpack(e0a, e0b); w1[g4] = bfpack(e0c, e0d);
                    x0[g4] = bfpack(e1a, e1b); x1[g4] = bfpack(e1c, e1d);
                }
            } else {
                #pragma unroll
                for (int g4 = 0; g4 < 4; ++g4) {
                    float e0a = EXP2F(s0[g4 * 4 + 0] - FIXED_M);
                    float e0b = EXP2F(s0[g4 * 4 + 1] - FIXED_M);
                    float e0c = EXP2F(s0[g4 * 4 + 2] - FIXED_M);
                    float e0d = EXP2F(s0[g4 * 4 + 3] - FIXED_M);
                    float e1a = EXP2F(s1[g4 * 4 + 0] - FIXED_M);
                    float e1b = EXP2F(s1[g4 * 4 + 1] - FIXED_M);
                    float e1c = EXP2F(s1[g4 * 4 + 2] - FIXED_M);
                    float e1d = EXP2F(s1[g4 * 4 + 3] - FIXED_M);
                    ps += (e0a + e0b) + (e0c + e0d) + (e1a + e1b) + (e1c + e1d);
                    w0[g4] = bfpack(e0a, e0b); w1[g4] = bfpack(e0c, e0d);
                    x0[g4] = bfpack(e1a, e1b); x1[g4] = bfpack(e1c, e1d);
                }
            }
            ps += __shfl_xor(ps, 32);
            lr += ps;

            // in-register P^T fragment build: one swap fills two output words
            pl32swap(w0[0], w0[1]); pl32swap(w1[0], w1[1]);   // -> pf0
            pl32swap(w0[2], w0[3]); pl32swap(w1[2], w1[3]);   // -> pf1
            pl32swap(x0[0], x0[1]); pl32swap(x1[0], x1[1]);   // -> pf2
            pl32swap(x0[2], x0[3]); pl32swap(x1[2], x1[3]);   // -> pf3
            s8v pf0 = mkfrag(w0[0], w1[0], w0[1], w1[1]);
            s8v pf1 = mkfrag(w0[2], w1[2], w0[3], w1[3]);
            s8v pf2 = mkfrag(x0[0], x1[0], x0[1], x1[1]);
            s8v pf3 = mkfrag(x0[2], x1[2], x0[3], x1[3]);

            // O^T += V^T P^T : rows=d (2 tiles of 32), col=q
            acco0 = __builtin_amdgcn_mfma_f32_32x32x16_bf16(av0[0], pf0, acco0, 0, 0, 0);
            acco1 = __builtin_amdgcn_mfma_f32_32x32x16_bf16(av1[0], pf0, acco1, 0, 0, 0);
            acco0 = __builtin_amdgcn_mfma_f32_32x32x16_bf16(av0[1], pf1, acco0, 0, 0, 0);
            acco1 = __builtin_amdgcn_mfma_f32_32x32x16_bf16(av1[1], pf1, acco1, 0, 0, 0);
            acco0 = __builtin_amdgcn_mfma_f32_32x32x16_bf16(av0[2], pf2, acco0, 0, 0, 0);
            acco1 = __builtin_amdgcn_mfma_f32_32x32x16_bf16(av1[2], pf2, acco1, 0, 0, 0);
            acco0 = __builtin_amdgcn_mfma_f32_32x32x16_bf16(av0[3], pf3, acco0, 0, 0, 0);
            acco1 = __builtin_amdgcn_mfma_f32_32x32x16_bf16(av1[3], pf3, acco1, 0, 0, 0);
        }

        __syncthreads();   // waves done with buf; DMAs for buf^1 drained here
    }

    // ---- epilogue: LDS transpose (overlay K/V/P area) -> coalesced stores
    __syncthreads();
    float* LTw = (float*)SMEM + w * (32 * 68);
    const float inv = 1.0f / lr;
    #pragma unroll
    for (int r = 0; r < 16; ++r) {
        const int d = (r & 3) + 8 * (r >> 2) + 4 * hi;
        LTw[l31 * 68 + d] = acco0[r] * inv;
        LTw[l31 * 68 + 32 + d] = acco1[r] * inv;
    }
    // wave-private region; DS in-order. Read rows, store float4.
    const int qr4 = lane >> 4, chk = lane & 15;
    #pragma unroll
    for (int p = 0; p < 8; ++p) {
        const int qrow = p * 4 + qr4;
        f4v v = *(const f4v*)&LTw[qrow * 68 + chk * 4];
        *(float4*)(Y + (size_t)(b * 2048 + q0 + w * 32 + qrow) * 1024
                   + h * 64 + chk * 4) = (float4){v[0], v[1], v[2], v[3]};
    }
}

// ---------------------------------------------------------------------------
extern "C" void kernel_launch(void* const* d_in, const int* in_sizes, int n_in,
                              void* d_out, int out_size, void* d_ws,
                              size_t ws_size, hipStream_t stream)
{
    const float* x_qk = (const float*)d_in[0];
    const float* x_v  = (const float*)d_in[1];
    const float* W    = (const float*)d_in[2];
    const float* bias = (const float*)d_in[3];
    float* out = (float*)d_out;

    unsigned char* ws = (unsigned char*)d_ws;
    ush* Xb = (ush*)(ws);                  // 8 MB; dead after gemm
    ush* Vt = (ush*)(ws);                  // 8 MB; written after gemm
    ush* Wt = (ush*)(ws + (8u << 20));     // 4 MB
    ush* Qb = (ush*)(ws + (12u << 20));    // 8 MB
    ush* Kb = (ush*)(ws + (20u << 20));    // 8 MB (28 MB peak)

    prepA_kernel<<<2560, 256, 0, stream>>>(x_qk, W, Xb, Wt);
    gemm_kernel<<<dim3(16, 32), 256, 0, stream>>>(Xb, Wt, bias, Qb, Kb);
    vt_kernel<<<dim3(32, 32), 256, 0, stream>>>(x_v, Vt);
    attn_kernel<<<512, 256, 0, stream>>>(Qb, Kb, Vt, out);
}